// Round 18
// baseline (284.947 us; speedup 1.0000x reference)
//
#include <hip/hip_runtime.h>
#include <hip/hip_bf16.h>

#define ALPHA_ 0.2f
#define EPS_ 1e-12f

typedef short short8 __attribute__((ext_vector_type(8)));
typedef unsigned short ushort4v __attribute__((ext_vector_type(4)));
typedef float f32x4 __attribute__((ext_vector_type(4)));

constexpr int BB = 16, KK = 16, DD = 256, NNEG = 16384;

// ---- workspace layout (float offsets) ---- total 5,309,440 floats (proven size)
// Chain: P0=XA, R0=T; P1=XB, R1=S; P2=XA, R2=T; P3(final)=XB (never overlaid).
// After: NH (bf16 negatives, 2M floats) overlays T+S.
constexpr size_t OFF_XA_H  = 1048576;
constexpr size_t OFF_XA_L  = 1572864;
constexpr size_t OFF_XB_H  = 2097152;   // FINAL A hi (never overlaid)
constexpr size_t OFF_XB_L  = 2621440;
constexpr size_t OFF_NH    = 3145728;   // 2M floats: neg bf16 (overlays T+S)
constexpr size_t OFF_T_H   = 3145728;
constexpr size_t OFF_C01   = 3149824;   // c0[16], c1[16] (inside T; consumed before T written)
constexpr size_t OFF_T_L   = 3670016;
constexpr size_t OFF_S_H   = 4194304;
constexpr size_t OFF_S_L   = 4718592;
constexpr size_t OFF_PA_H  = 5242880;   // 65536 ushorts
constexpr size_t OFF_PA_L  = 5275648;
constexpr size_t OFF_PAP   = 5308416;
constexpr size_t OFF_DPOS2 = 5308672;
constexpr size_t OFF_MINA  = 5308928;
constexpr size_t OFF_MINV  = 5309184;

// ---------- bf16 split helpers (RNE) ----------
__device__ inline unsigned short bf_hi(float x) {
    unsigned u = __float_as_uint(x);
    return (unsigned short)((u + 0x7fffu + ((u >> 16) & 1u)) >> 16);
}
__device__ inline float bf_tof(unsigned short h) { return __uint_as_float(((unsigned)h) << 16); }
__device__ inline void split2(float x, unsigned short& h, unsigned short& l) {
    h = bf_hi(x); l = bf_hi(x - bf_tof(h));
}

// ---------- bound: Gershgorin + 6-step power iteration -> degree-2 init coefficients ----------
__global__ __launch_bounds__(256) void kbound(const float* __restrict__ Sig, float* __restrict__ c01) {
    int b = blockIdx.x, t = threadIdx.x;
    const float* S = Sig + (size_t)b * 65536;
    __shared__ float v[256];
    __shared__ float red[256];
    float cs = 0.f;
    for (int i = 0; i < 256; ++i) cs += fabsf(S[(size_t)i * 256 + t]);
    red[t] = cs; __syncthreads();
    for (int s = 128; s > 0; s >>= 1) { if (t < s) red[t] = fmaxf(red[t], red[t + s]); __syncthreads(); }
    float G = red[0]; __syncthreads();
    v[t] = 1.f; __syncthreads();
    for (int it = 0; it < 6; ++it) {
        float wv = 0.f;
        for (int i = 0; i < 256; ++i) wv = fmaf(S[(size_t)i * 256 + t], v[i], wv);
        red[t] = wv * wv; __syncthreads();
        for (int s = 128; s > 0; s >>= 1) { if (t < s) red[t] += red[t + s]; __syncthreads(); }
        float nrm = sqrtf(red[0]); __syncthreads();
        v[t] = wv / nrm; __syncthreads();
    }
    float w2 = 0.f;
    for (int i = 0; i < 256; ++i) w2 = fmaf(S[(size_t)i * 256 + t], v[i], w2);
    red[t] = w2 * v[t]; __syncthreads();
    for (int s = 128; s > 0; s >>= 1) { if (t < s) red[t] += red[t + s]; __syncthreads(); }
    if (t == 0) {
        float lam = red[0];                         // Rayleigh quotient (<= lambda_max)
        float Bb = fminf(G, 1.06f * lam + 0.05f);   // safe upper estimate
        float c1 = -2.f / (Bb + (Bb + 1.f) * (Bb + 1.f) * 0.25f);
        c01[b] = -c1 * (Bb + 1.f); c01[16 + b] = c1;
    }
}

// ---------- prep: split S; P0 = X0 = c0*I + c1*S -> XA (split) ----------
__global__ __launch_bounds__(256) void kinit(const float* __restrict__ Sig, float* __restrict__ ws,
                                             const float* __restrict__ c01) {
    int idx = blockIdx.x * 256 + threadIdx.x;
    int b = idx >> 16, rc = idx & 65535;
    int r = rc >> 8, c = rc & 255;
    float v = Sig[idx];
    unsigned short h, l;
    split2(v, h, l);
    ((unsigned short*)(ws + OFF_S_H))[idx] = h; ((unsigned short*)(ws + OFF_S_L))[idx] = l;
    float x0 = c01[16 + b] * v + ((r == c) ? c01[b] : 0.f);
    split2(x0, h, l);
    ((unsigned short*)(ws + OFF_XA_H))[idx] = h; ((unsigned short*)(ws + OFF_XA_L))[idx] = l;
}

// ---------- Newton-squaring matmul, LDS-staged (r16-proven verbatim) ----------
__global__ __launch_bounds__(256) void kmm(const unsigned short* __restrict__ PAh,
                                           const unsigned short* __restrict__ PAl,
                                           const unsigned short* __restrict__ PBh,
                                           const unsigned short* __restrict__ PBl,
                                           unsigned short* __restrict__ POh,
                                           unsigned short* __restrict__ POl, int pmode,
                                           const unsigned short* __restrict__ Rh,
                                           const unsigned short* __restrict__ Rl,
                                           unsigned short* __restrict__ ROh,
                                           unsigned short* __restrict__ ROl) {
    __shared__ unsigned short pAh[32 * 256];
    __shared__ unsigned short pAl[32 * 256];
    __shared__ unsigned short pBh[32 * 256];
    __shared__ unsigned short pBl[32 * 256];

    int lin = blockIdx.x;
    int x = lin & 7, qq = lin >> 3;
    int isP = (qq < 128) ? 1 : 0;
    int q2 = isP ? qq : (qq - 128);
    int b = x * 2 + (q2 >> 6);
    int tile = q2 & 63;
    int i0 = (tile >> 3) * 32, j0 = (tile & 7) * 32;
    size_t base = (size_t)b * 65536;
    const unsigned short* Ah = isP ? PAh : Rh;
    const unsigned short* Al = isP ? PAl : Rl;
    const unsigned short* Bh = isP ? PBh : Rh;
    const unsigned short* Bl = isP ? PBl : Rl;
    unsigned short* Ch = isP ? POh : ROh;
    unsigned short* Cl = isP ? POl : ROl;

    int t = threadIdx.x;
    {
        int row = t >> 3, oc = t & 7, rsw = row & 7;
        const unsigned short* gah = Ah + base + (size_t)(i0 + row) * 256 + oc * 32;
        const unsigned short* gal = Al + base + (size_t)(i0 + row) * 256 + oc * 32;
        const unsigned short* gbh = Bh + base + (size_t)(j0 + row) * 256 + oc * 32;
        const unsigned short* gbl = Bl + base + (size_t)(j0 + row) * 256 + oc * 32;
        #pragma unroll
        for (int k = 0; k < 4; ++k) {
            int sb = (((oc * 4 + k) ^ rsw)) * 8;
            *reinterpret_cast<short8*>(pAh + row * 256 + sb) = *reinterpret_cast<const short8*>(gah + k * 8);
            *reinterpret_cast<short8*>(pAl + row * 256 + sb) = *reinterpret_cast<const short8*>(gal + k * 8);
            *reinterpret_cast<short8*>(pBh + row * 256 + sb) = *reinterpret_cast<const short8*>(gbh + k * 8);
            *reinterpret_cast<short8*>(pBl + row * 256 + sb) = *reinterpret_cast<const short8*>(gbl + k * 8);
        }
    }
    __syncthreads();

    int lane = t & 63, w = t >> 6;
    int wi = w & 1, wj = w >> 1;
    int l15 = lane & 15, lg = lane >> 4;
    int rs = l15 & 7;
    int ra = (wi * 16 + l15) * 256;
    int rb = (wj * 16 + l15) * 256;
    f32x4 acc0 = {}, acc1 = {};
    #pragma unroll
    for (int c = 0; c < 8; ++c) {
        int eb = ((c * 4 + lg) ^ rs) * 8;
        short8 a_h = *reinterpret_cast<const short8*>(pAh + ra + eb);
        short8 a_l = *reinterpret_cast<const short8*>(pAl + ra + eb);
        short8 b_h = *reinterpret_cast<const short8*>(pBh + rb + eb);
        short8 b_l = *reinterpret_cast<const short8*>(pBl + rb + eb);
        if (c & 1) {
            acc1 = __builtin_amdgcn_mfma_f32_16x16x32_bf16(a_h, b_h, acc1, 0, 0, 0);
            acc1 = __builtin_amdgcn_mfma_f32_16x16x32_bf16(a_h, b_l, acc1, 0, 0, 0);
            acc1 = __builtin_amdgcn_mfma_f32_16x16x32_bf16(a_l, b_h, acc1, 0, 0, 0);
        } else {
            acc0 = __builtin_amdgcn_mfma_f32_16x16x32_bf16(a_h, b_h, acc0, 0, 0, 0);
            acc0 = __builtin_amdgcn_mfma_f32_16x16x32_bf16(a_h, b_l, acc0, 0, 0, 0);
            acc0 = __builtin_amdgcn_mfma_f32_16x16x32_bf16(a_l, b_h, acc0, 0, 0, 0);
        }
    }
    #pragma unroll
    for (int r = 0; r < 4; ++r) {
        int row = i0 + wi * 16 + 4 * lg + r;
        int col = j0 + wj * 16 + l15;
        float v = acc0[r] + acc1[r];
        size_t off = base + (size_t)row * 256 + col;
        if (isP) {
            if (pmode == 2) v = ((row == col) ? 1.f : 0.f) - v;
            else            v += bf_tof(PAh[off]) + bf_tof(PAl[off]);
        }
        unsigned short h, l; split2(v, h, l);
        Ch[off] = h; Cl[off] = l;
    }
}

// ---------- fused aux: blocks 0..2047 = negatives bf16 + min init; 2048.. = k2 ----------
__global__ __launch_bounds__(256) void kaux(const float* __restrict__ negs,
                                            unsigned short* __restrict__ NH,
                                            unsigned* __restrict__ mina,
                                            unsigned* __restrict__ minv,
                                            const float* __restrict__ Z1,
                                            const float* __restrict__ Z2,
                                            const int* __restrict__ match,
                                            const unsigned short* __restrict__ AH,
                                            const unsigned short* __restrict__ AL,
                                            float* __restrict__ ws) {
    __shared__ float z[DD], df[DD];
    __shared__ float red[256];
    int blk = blockIdx.x, t = threadIdx.x;
    if (blk < 2048) {
        size_t i8 = ((size_t)blk * 256 + t) * 8;
        f32x4 v0 = *reinterpret_cast<const f32x4*>(negs + i8);
        f32x4 v1 = *reinterpret_cast<const f32x4*>(negs + i8 + 4);
        short8 h;
        #pragma unroll
        for (int j = 0; j < 4; ++j) {
            h[j] = (short)bf_hi(v0[j]);
            h[4 + j] = (short)bf_hi(v1[j]);
        }
        *reinterpret_cast<short8*>(NH + i8) = h;
        if (blk == 0) { mina[t] = 0x7f800000u; minv[t] = 0x7f800000u; }
        return;
    }
    int bk = blk - 2048; int b = bk >> 4;
    const unsigned short* Ah = AH + (size_t)b * 65536;
    const unsigned short* Al = AL + (size_t)b * 65536;
    int m = match[bk];
    float zv = Z1[(size_t)bk * DD + t];
    float qv = Z2[((size_t)b * KK + m) * DD + t];
    z[t] = zv; df[t] = zv - qv;
    __syncthreads();
    float pa = 0.f, da = 0.f;
    for (int e = 0; e < DD; ++e) {
        float Ae = bf_tof(Ah[(size_t)e * 256 + t]) + bf_tof(Al[(size_t)e * 256 + t]);
        pa = fmaf(z[e], Ae, pa);
        da = fmaf(df[e], Ae, da);
    }
    unsigned short ph, pl; split2(pa, ph, pl);
    ((unsigned short*)(ws + OFF_PA_H))[(size_t)bk * 256 + t] = ph;
    ((unsigned short*)(ws + OFF_PA_L))[(size_t)bk * 256 + t] = pl;
    float dfv = df[t];
    red[t] = pa * zv; __syncthreads();
    for (int s = 128; s > 0; s >>= 1) { if (t < s) red[t] += red[t + s]; __syncthreads(); }
    float pAp = red[0]; __syncthreads();
    red[t] = da * dfv; __syncthreads();
    for (int s = 128; s > 0; s >>= 1) { if (t < s) red[t] += red[t + s]; __syncthreads(); }
    if (t == 0) {
        ws[OFF_PAP + bk]   = pAp;
        ws[OFF_DPOS2 + bk] = fmaxf(red[0], EPS_);
    }
}

// ---------- main kernel: n-tile 64, 2-product, lean regs -> 2 blocks/CU, 4-bit swizzle ----------
// 4096 blocks x 512 thr = 8 waves, zero-barrier loop. Wave w: f-tiles {2w,2w+1}, 4 n-subtiles j.
// PA on wave w (w<4) for j==w. LDS 32 KB neg tile + 6.7 KB epilogue.
__global__ __launch_bounds__(512) void k3(const unsigned short* __restrict__ Ahi,
                                          const unsigned short* __restrict__ Alo,
                                          const unsigned short* __restrict__ PAh,
                                          const unsigned short* __restrict__ PAl,
                                          const unsigned short* __restrict__ NH,
                                          const float* __restrict__ pap,
                                          const float* __restrict__ dpos2,
                                          unsigned* __restrict__ mina,
                                          unsigned* __restrict__ minv) {
    __shared__ unsigned short Bh[64 * 256];            // 32 KB, 16B-block XOR(row&15)-swizzled
    __shared__ float ep[1664];                         // 6.7 KB epilogue

    int lin = blockIdx.x;
    int x  = lin & 7;
    int q  = lin >> 3;
    int b  = q >> 5;
    int n0 = (x * 32 + (q & 31)) * 64;                 // XCD-local 2048-n slice
    int t = threadIdx.x, lane = t & 63, w = t >> 6;
    int l15 = lane & 15, lg = lane >> 4;
    const unsigned short* Ab  = Ahi + (size_t)b * 65536;
    const unsigned short* Al_ = Alo + (size_t)b * 65536;
    const unsigned short* Nh  = NH + (size_t)n0 * 256;

    {   // one-shot swizzled staging of the 64x256 bf16 negative tile
        int row = t >> 3, oc = t & 7, rsw = row & 15;
        const unsigned short* gh = Nh + (size_t)row * 256 + oc * 32;
        #pragma unroll
        for (int k = 0; k < 4; ++k) {
            int sblk = (oc * 4 + k) ^ rsw;
            *reinterpret_cast<short8*>(Bh + row * 256 + sblk * 8) =
                *reinterpret_cast<const short8*>(gh + k * 8);
        }
    }
    __syncthreads();                                   // the ONLY pre-compute barrier

    const unsigned short* aBh = Ab  + (size_t)(w * 32 + l15) * 256 + 8 * lg;
    const unsigned short* aBl = Al_ + (size_t)(w * 32 + l15) * 256 + 8 * lg;
    const unsigned short* pph = PAh + (size_t)b * 4096 + (size_t)l15 * 256 + 8 * lg;
    const unsigned short* ppl = PAl + (size_t)b * 4096 + (size_t)l15 * 256 + 8 * lg;

    f32x4 acc0[4] = {}, acc1[4] = {};
    f32x4 accp = {};
    int rs0 = l15;                                     // 4-bit read swizzle

    #pragma unroll
    for (int c = 0; c < 8; ++c) {
        short8 ah0 = *reinterpret_cast<const short8*>(aBh + c * 32);
        short8 al0 = *reinterpret_cast<const short8*>(aBl + c * 32);
        short8 ah1 = *reinterpret_cast<const short8*>(aBh + 16 * 256 + c * 32);
        short8 al1 = *reinterpret_cast<const short8*>(aBl + 16 * 256 + c * 32);
        short8 ph_ = {}, pl_ = {};
        if (w < 4) {
            ph_ = *reinterpret_cast<const short8*>(pph + c * 32);
            pl_ = *reinterpret_cast<const short8*>(ppl + c * 32);
        }
        #pragma unroll
        for (int j = 0; j < 4; ++j) {
            int ro = (j * 16 + l15) * 256 + (((c * 4 + lg) ^ rs0) * 8);
            short8 bh = *reinterpret_cast<const short8*>(Bh + ro);
            acc0[j] = __builtin_amdgcn_mfma_f32_16x16x32_bf16(ah0, bh, acc0[j], 0, 0, 0);
            acc0[j] = __builtin_amdgcn_mfma_f32_16x16x32_bf16(al0, bh, acc0[j], 0, 0, 0);
            acc1[j] = __builtin_amdgcn_mfma_f32_16x16x32_bf16(ah1, bh, acc1[j], 0, 0, 0);
            acc1[j] = __builtin_amdgcn_mfma_f32_16x16x32_bf16(al1, bh, acc1[j], 0, 0, 0);
            if (w == j) {                              // w<4 implied
                accp = __builtin_amdgcn_mfma_f32_16x16x32_bf16(ph_, bh, accp, 0, 0, 0);
                accp = __builtin_amdgcn_mfma_f32_16x16x32_bf16(pl_, bh, accp, 0, 0, 0);
            }
        }
    }

    float* pAn_l = ep;              // [64][17] = 1088 (live until d2 loop done)
    float* nAnp  = ep + 1088;       // [8][64] = 512 (dead after nAn reduce)
    float* nAn_l = ep + 1600;       // [64]
    float* reda  = ep + 1088;       // aliases nAnp (written after consumed)
    float* redv  = ep + 1344;       // aliases nAnp upper half

    if (w < 4) {                                        // pAn for n = w*16+l15, k = 4lg+r
        #pragma unroll
        for (int r = 0; r < 4; ++r)
            pAn_l[(w * 16 + l15) * 17 + 4 * lg + r] = accp[r];
    }
    int bb = w * 4 + (lg >> 1);
    int sub = (lg & 1) * 4;
    #pragma unroll
    for (int j = 0; j < 4; ++j) {
        int n = j * 16 + l15;
        float p = 0.f;
        {
            ushort4v wh0 = *reinterpret_cast<const ushort4v*>(Bh + n * 256 + ((bb    ) ^ rs0) * 8 + sub);
            ushort4v wh1 = *reinterpret_cast<const ushort4v*>(Bh + n * 256 + ((bb + 2) ^ rs0) * 8 + sub);
            #pragma unroll
            for (int r = 0; r < 4; ++r) {
                p = fmaf(acc0[j][r], bf_tof(wh0[r]), p);
                p = fmaf(acc1[j][r], bf_tof(wh1[r]), p);
            }
        }
        p += __shfl_xor(p, 16);
        p += __shfl_xor(p, 32);
        if (lane < 16) nAnp[w * 64 + n] = p;
    }
    __syncthreads();
    if (t < 64) {
        float s = 0.f;
        #pragma unroll
        for (int ww = 0; ww < 8; ++ww) s += nAnp[ww * 64 + t];
        nAn_l[t] = s;
    }
    __syncthreads();                                   // nAnp consumed; reda/redv may overwrite
    if (t < 256) {
        int tx = t & 15, ty = t >> 4;                  // ty 0..15, 4 n each
        float pApk = pap[b * 16 + tx];
        float dp2  = dpos2[b * 16 + tx];
        float mn_a = __uint_as_float(0x7f800000u), mn_v = mn_a;
        #pragma unroll
        for (int ii = 0; ii < 4; ++ii) {
            int n = ty * 4 + ii;
            float d2v = pApk - 2.f * pAn_l[n * 17 + tx] + nAn_l[n];
            float cc = fmaxf(d2v, EPS_);
            mn_a = fminf(mn_a, cc);
            if (cc > dp2) mn_v = fminf(mn_v, cc);
        }
        reda[ty * 16 + tx] = mn_a; redv[ty * 16 + tx] = mn_v;
    }
    __syncthreads();
    if (t < 16) {
        float ra = reda[t], rv = redv[t];
        #pragma unroll
        for (int y = 1; y < 16; ++y) {
            ra = fminf(ra, reda[y * 16 + t]);
            rv = fminf(rv, redv[y * 16 + t]);
        }
        atomicMin(&mina[b * 16 + t], __float_as_uint(ra));
        atomicMin(&minv[b * 16 + t], __float_as_uint(rv));
    }
}

// ---------- final loss ----------
__global__ __launch_bounds__(256) void k5(const float* __restrict__ dpos2,
                                          const unsigned* __restrict__ mina,
                                          const unsigned* __restrict__ minv,
                                          float* __restrict__ out) {
    int t = threadIdx.x;
    __shared__ float red[256];
    float dp = sqrtf(dpos2[t]);
    unsigned mv = minv[t], ma = mina[t];
    unsigned sel = (mv < 0x7f800000u) ? mv : ma;
    float dn = sqrtf(__uint_as_float(sel));
    red[t] = fmaxf(dp - dn + ALPHA_, 0.f);
    __syncthreads();
    for (int s = 128; s > 0; s >>= 1) { if (t < s) red[t] += red[t + s]; __syncthreads(); }
    if (t == 0) out[0] = red[0] * (1.f / 256.f);
}

extern "C" void kernel_launch(void* const* d_in, const int* in_sizes, int n_in,
                              void* d_out, int out_size, void* d_ws, size_t ws_size,
                              hipStream_t stream) {
    (void)in_sizes; (void)n_in; (void)out_size; (void)ws_size;
    const float* Z1   = (const float*)d_in[0];
    const float* Z2   = (const float*)d_in[1];
    const int*   mat  = (const int*)d_in[2];
    const float* negs = (const float*)d_in[3];
    const float* Sig  = (const float*)d_in[4];
    float* ws = (float*)d_ws;
    unsigned short* S_H  = (unsigned short*)(ws + OFF_S_H);
    unsigned short* S_L  = (unsigned short*)(ws + OFF_S_L);
    unsigned short* XA_H = (unsigned short*)(ws + OFF_XA_H);
    unsigned short* XA_L = (unsigned short*)(ws + OFF_XA_L);
    unsigned short* XB_H = (unsigned short*)(ws + OFF_XB_H);
    unsigned short* XB_L = (unsigned short*)(ws + OFF_XB_L);
    unsigned short* T_H  = (unsigned short*)(ws + OFF_T_H);
    unsigned short* T_L  = (unsigned short*)(ws + OFF_T_L);
    unsigned short* PA_H = (unsigned short*)(ws + OFF_PA_H);
    unsigned short* PA_L = (unsigned short*)(ws + OFF_PA_L);
    unsigned short* NH   = (unsigned short*)(ws + OFF_NH);
    unsigned* mina = (unsigned*)(ws + OFF_MINA);
    unsigned* minv = (unsigned*)(ws + OFF_MINV);
    float* out = (float*)d_out;

    kbound<<<BB, 256, 0, stream>>>(Sig, ws + OFF_C01);        // power-iter bound -> c0,c1
    kinit<<<4096, 256, 0, stream>>>(Sig, ws, ws + OFF_C01);   // split S; P0 = X0 -> XA

    // R0 = I - S@P0 -> T
    kmm<<<1024, 256, 0, stream>>>(S_H, S_L, XA_H, XA_L, T_H, T_L, 2, S_H, S_L, T_H, T_L);
    // stage 0: P1 = P0 + P0@R0 -> XB ; R1 = R0^2 -> S
    kmm<<<2048, 256, 0, stream>>>(XA_H, XA_L, T_H, T_L, XB_H, XB_L, 3, T_H, T_L, S_H, S_L);
    // stage 1: P2 = P1 + P1@R1 -> XA ; R2 = R1^2 -> T
    kmm<<<2048, 256, 0, stream>>>(XB_H, XB_L, S_H, S_L, XA_H, XA_L, 3, S_H, S_L, T_H, T_L);
    // stage 2: P3 = P2 + P2@R2 -> XB (FINAL A); residual = R0^8 ~ 8e-5
    kmm<<<1024, 256, 0, stream>>>(XA_H, XA_L, T_H, T_L, XB_H, XB_L, 3, S_H, S_L, T_H, T_L);

    // fused: negatives bf16 (+min init) and k2 in one dispatch
    kaux<<<2048 + BB * KK, 256, 0, stream>>>(negs, NH, mina, minv,
                                             Z1, Z2, mat, XB_H, XB_L, ws);
    k3<<<BB * NNEG / 64, 512, 0, stream>>>(XB_H, XB_L, PA_H, PA_L, NH,
                                           ws + OFF_PAP, ws + OFF_DPOS2, mina, minv);
    k5<<<1, 256, 0, stream>>>(ws + OFF_DPOS2, mina, minv, out);
}

// Round 19
// 251.825 us; speedup vs baseline: 1.1315x; 1.1315x over previous
//
#include <hip/hip_runtime.h>
#include <hip/hip_bf16.h>

#define ALPHA_ 0.2f
#define EPS_ 1e-12f

typedef short short8 __attribute__((ext_vector_type(8)));
typedef unsigned short ushort4v __attribute__((ext_vector_type(4)));
typedef float f32x4 __attribute__((ext_vector_type(4)));

constexpr int BB = 16, KK = 16, DD = 256, NNEG = 16384;

// ---- workspace layout (float offsets) ---- total 5,309,440 floats (proven size)
// Chain: P0=XA, R0=T; P1=XB, R1=S; P2=XA, R2=T; P3(final)=XB (never overlaid).
// After chain: AF (frag-layout A) overlays XA; NH (bf16 negs) overlays T+S.
constexpr size_t OFF_AF_H  = 1048576;   // frag-layout A hi (overlays XA_H)
constexpr size_t OFF_XA_H  = 1048576;
constexpr size_t OFF_AF_L  = 1572864;   // frag-layout A lo (overlays XA_L)
constexpr size_t OFF_XA_L  = 1572864;
constexpr size_t OFF_XB_H  = 2097152;   // FINAL A hi (std layout; never overlaid)
constexpr size_t OFF_XB_L  = 2621440;
constexpr size_t OFF_NH    = 3145728;   // 2M floats: neg bf16 (overlays T+S)
constexpr size_t OFF_T_H   = 3145728;
constexpr size_t OFF_C01   = 3149824;   // c0[16], c1[16] (inside T; consumed before T written)
constexpr size_t OFF_T_L   = 3670016;
constexpr size_t OFF_S_H   = 4194304;
constexpr size_t OFF_S_L   = 4718592;
constexpr size_t OFF_PA_H  = 5242880;   // 65536 ushorts (FRAG layout)
constexpr size_t OFF_PA_L  = 5275648;
constexpr size_t OFF_PAP   = 5308416;
constexpr size_t OFF_DPOS2 = 5308672;
constexpr size_t OFF_MINA  = 5308928;
constexpr size_t OFF_MINV  = 5309184;

// ---------- bf16 split helpers (RNE) ----------
__device__ inline unsigned short bf_hi(float x) {
    unsigned u = __float_as_uint(x);
    return (unsigned short)((u + 0x7fffu + ((u >> 16) & 1u)) >> 16);
}
__device__ inline float bf_tof(unsigned short h) { return __uint_as_float(((unsigned)h) << 16); }
__device__ inline void split2(float x, unsigned short& h, unsigned short& l) {
    h = bf_hi(x); l = bf_hi(x - bf_tof(h));
}

// ---------- bound: Gershgorin + 12-step power iteration -> degree-2 init coefficients ----------
__global__ __launch_bounds__(256) void kbound(const float* __restrict__ Sig, float* __restrict__ c01) {
    int b = blockIdx.x, t = threadIdx.x;
    const float* S = Sig + (size_t)b * 65536;
    __shared__ float v[256];
    __shared__ float red[256];
    float cs = 0.f;
    for (int i = 0; i < 256; ++i) cs += fabsf(S[(size_t)i * 256 + t]);
    red[t] = cs; __syncthreads();
    for (int s = 128; s > 0; s >>= 1) { if (t < s) red[t] = fmaxf(red[t], red[t + s]); __syncthreads(); }
    float G = red[0]; __syncthreads();
    v[t] = 1.f; __syncthreads();
    for (int it = 0; it < 12; ++it) {
        float wv = 0.f;
        for (int i = 0; i < 256; ++i) wv = fmaf(S[(size_t)i * 256 + t], v[i], wv);
        red[t] = wv * wv; __syncthreads();
        for (int s = 128; s > 0; s >>= 1) { if (t < s) red[t] += red[t + s]; __syncthreads(); }
        float nrm = sqrtf(red[0]); __syncthreads();
        v[t] = wv / nrm; __syncthreads();
    }
    float w2 = 0.f;
    for (int i = 0; i < 256; ++i) w2 = fmaf(S[(size_t)i * 256 + t], v[i], w2);
    red[t] = w2 * v[t]; __syncthreads();
    for (int s = 128; s > 0; s >>= 1) { if (t < s) red[t] += red[t + s]; __syncthreads(); }
    if (t == 0) {
        float lam = red[0];                         // Rayleigh quotient (<= lambda_max)
        float Bb = fminf(G, 1.06f * lam + 0.05f);   // safe upper estimate
        float c1 = -2.f / (Bb + (Bb + 1.f) * (Bb + 1.f) * 0.25f);
        c01[b] = -c1 * (Bb + 1.f); c01[16 + b] = c1;
    }
}

// ---------- prep: split S; P0 = X0 = c0*I + c1*S -> XA (split) ----------
__global__ __launch_bounds__(256) void kinit(const float* __restrict__ Sig, float* __restrict__ ws,
                                             const float* __restrict__ c01) {
    int idx = blockIdx.x * 256 + threadIdx.x;
    int b = idx >> 16, rc = idx & 65535;
    int r = rc >> 8, c = rc & 255;
    float v = Sig[idx];
    unsigned short h, l;
    split2(v, h, l);
    ((unsigned short*)(ws + OFF_S_H))[idx] = h; ((unsigned short*)(ws + OFF_S_L))[idx] = l;
    float x0 = c01[16 + b] * v + ((r == c) ? c01[b] : 0.f);
    split2(x0, h, l);
    ((unsigned short*)(ws + OFF_XA_H))[idx] = h; ((unsigned short*)(ws + OFF_XA_L))[idx] = l;
}

// ---------- Newton-squaring matmul, LDS-staged (r16-proven verbatim) ----------
__global__ __launch_bounds__(256) void kmm(const unsigned short* __restrict__ PAh,
                                           const unsigned short* __restrict__ PAl,
                                           const unsigned short* __restrict__ PBh,
                                           const unsigned short* __restrict__ PBl,
                                           unsigned short* __restrict__ POh,
                                           unsigned short* __restrict__ POl, int pmode,
                                           const unsigned short* __restrict__ Rh,
                                           const unsigned short* __restrict__ Rl,
                                           unsigned short* __restrict__ ROh,
                                           unsigned short* __restrict__ ROl) {
    __shared__ unsigned short pAh[32 * 256];
    __shared__ unsigned short pAl[32 * 256];
    __shared__ unsigned short pBh[32 * 256];
    __shared__ unsigned short pBl[32 * 256];

    int lin = blockIdx.x;
    int x = lin & 7, qq = lin >> 3;
    int isP = (qq < 128) ? 1 : 0;
    int q2 = isP ? qq : (qq - 128);
    int b = x * 2 + (q2 >> 6);
    int tile = q2 & 63;
    int i0 = (tile >> 3) * 32, j0 = (tile & 7) * 32;
    size_t base = (size_t)b * 65536;
    const unsigned short* Ah = isP ? PAh : Rh;
    const unsigned short* Al = isP ? PAl : Rl;
    const unsigned short* Bh = isP ? PBh : Rh;
    const unsigned short* Bl = isP ? PBl : Rl;
    unsigned short* Ch = isP ? POh : ROh;
    unsigned short* Cl = isP ? POl : ROl;

    int t = threadIdx.x;
    {
        int row = t >> 3, oc = t & 7, rsw = row & 7;
        const unsigned short* gah = Ah + base + (size_t)(i0 + row) * 256 + oc * 32;
        const unsigned short* gal = Al + base + (size_t)(i0 + row) * 256 + oc * 32;
        const unsigned short* gbh = Bh + base + (size_t)(j0 + row) * 256 + oc * 32;
        const unsigned short* gbl = Bl + base + (size_t)(j0 + row) * 256 + oc * 32;
        #pragma unroll
        for (int k = 0; k < 4; ++k) {
            int sb = (((oc * 4 + k) ^ rsw)) * 8;
            *reinterpret_cast<short8*>(pAh + row * 256 + sb) = *reinterpret_cast<const short8*>(gah + k * 8);
            *reinterpret_cast<short8*>(pAl + row * 256 + sb) = *reinterpret_cast<const short8*>(gal + k * 8);
            *reinterpret_cast<short8*>(pBh + row * 256 + sb) = *reinterpret_cast<const short8*>(gbh + k * 8);
            *reinterpret_cast<short8*>(pBl + row * 256 + sb) = *reinterpret_cast<const short8*>(gbl + k * 8);
        }
    }
    __syncthreads();

    int lane = t & 63, w = t >> 6;
    int wi = w & 1, wj = w >> 1;
    int l15 = lane & 15, lg = lane >> 4;
    int rs = l15 & 7;
    int ra = (wi * 16 + l15) * 256;
    int rb = (wj * 16 + l15) * 256;
    f32x4 acc0 = {}, acc1 = {};
    #pragma unroll
    for (int c = 0; c < 8; ++c) {
        int eb = ((c * 4 + lg) ^ rs) * 8;
        short8 a_h = *reinterpret_cast<const short8*>(pAh + ra + eb);
        short8 a_l = *reinterpret_cast<const short8*>(pAl + ra + eb);
        short8 b_h = *reinterpret_cast<const short8*>(pBh + rb + eb);
        short8 b_l = *reinterpret_cast<const short8*>(pBl + rb + eb);
        if (c & 1) {
            acc1 = __builtin_amdgcn_mfma_f32_16x16x32_bf16(a_h, b_h, acc1, 0, 0, 0);
            acc1 = __builtin_amdgcn_mfma_f32_16x16x32_bf16(a_h, b_l, acc1, 0, 0, 0);
            acc1 = __builtin_amdgcn_mfma_f32_16x16x32_bf16(a_l, b_h, acc1, 0, 0, 0);
        } else {
            acc0 = __builtin_amdgcn_mfma_f32_16x16x32_bf16(a_h, b_h, acc0, 0, 0, 0);
            acc0 = __builtin_amdgcn_mfma_f32_16x16x32_bf16(a_h, b_l, acc0, 0, 0, 0);
            acc0 = __builtin_amdgcn_mfma_f32_16x16x32_bf16(a_l, b_h, acc0, 0, 0, 0);
        }
    }
    #pragma unroll
    for (int r = 0; r < 4; ++r) {
        int row = i0 + wi * 16 + 4 * lg + r;
        int col = j0 + wj * 16 + l15;
        float v = acc0[r] + acc1[r];
        size_t off = base + (size_t)row * 256 + col;
        if (isP) {
            if (pmode == 2) v = ((row == col) ? 1.f : 0.f) - v;
            else            v += bf_tof(PAh[off]) + bf_tof(PAl[off]);
        }
        unsigned short h, l; split2(v, h, l);
        Ch[off] = h; Cl[off] = l;
    }
}

// ---------- repack A into MFMA-fragment layout: AF[b][e>>3][row][e&7] ----------
__global__ __launch_bounds__(256) void kpack(const unsigned short* __restrict__ XH,
                                             const unsigned short* __restrict__ XL,
                                             unsigned short* __restrict__ FH,
                                             unsigned short* __restrict__ FL) {
    int g = blockIdx.x * 256 + threadIdx.x;       // 512 blocks cover 16*256*32
    int b = g >> 13, rem = g & 8191;
    int row = rem >> 5, eb = rem & 31;
    size_t src = (size_t)b * 65536 + (size_t)row * 256 + eb * 8;   // coalesced read
    size_t dst = (size_t)b * 65536 + (size_t)eb * 2048 + row * 8;  // 16B-chunk write
    *reinterpret_cast<short8*>(FH + dst) = *reinterpret_cast<const short8*>(XH + src);
    *reinterpret_cast<short8*>(FL + dst) = *reinterpret_cast<const short8*>(XL + src);
}

// ---------- fused aux: blocks 0..2047 = negatives bf16 + min init; 2048.. = k2 ----------
// k2 part writes PA in FRAG layout: PAF[b][e>>3][k][e&7].
__global__ __launch_bounds__(256) void kaux(const float* __restrict__ negs,
                                            unsigned short* __restrict__ NH,
                                            unsigned* __restrict__ mina,
                                            unsigned* __restrict__ minv,
                                            const float* __restrict__ Z1,
                                            const float* __restrict__ Z2,
                                            const int* __restrict__ match,
                                            const unsigned short* __restrict__ AH,
                                            const unsigned short* __restrict__ AL,
                                            float* __restrict__ ws) {
    __shared__ float z[DD], df[DD];
    __shared__ float red[256];
    int blk = blockIdx.x, t = threadIdx.x;
    if (blk < 2048) {
        size_t i8 = ((size_t)blk * 256 + t) * 8;
        f32x4 v0 = *reinterpret_cast<const f32x4*>(negs + i8);
        f32x4 v1 = *reinterpret_cast<const f32x4*>(negs + i8 + 4);
        short8 h;
        #pragma unroll
        for (int j = 0; j < 4; ++j) {
            h[j] = (short)bf_hi(v0[j]);
            h[4 + j] = (short)bf_hi(v1[j]);
        }
        *reinterpret_cast<short8*>(NH + i8) = h;
        if (blk == 0) { mina[t] = 0x7f800000u; minv[t] = 0x7f800000u; }
        return;
    }
    int bk = blk - 2048; int b = bk >> 4; int k = bk & 15;
    const unsigned short* Ah = AH + (size_t)b * 65536;
    const unsigned short* Al = AL + (size_t)b * 65536;
    int m = match[bk];
    float zv = Z1[(size_t)bk * DD + t];
    float qv = Z2[((size_t)b * KK + m) * DD + t];
    z[t] = zv; df[t] = zv - qv;
    __syncthreads();
    float pa = 0.f, da = 0.f;
    for (int e = 0; e < DD; ++e) {
        float Ae = bf_tof(Ah[(size_t)e * 256 + t]) + bf_tof(Al[(size_t)e * 256 + t]);
        pa = fmaf(z[e], Ae, pa);
        da = fmaf(df[e], Ae, da);
    }
    unsigned short ph, pl; split2(pa, ph, pl);
    size_t pidx = (size_t)b * 4096 + (size_t)(t >> 3) * 128 + k * 8 + (t & 7);  // frag layout
    ((unsigned short*)(ws + OFF_PA_H))[pidx] = ph;
    ((unsigned short*)(ws + OFF_PA_L))[pidx] = pl;
    float dfv = df[t];
    red[t] = pa * zv; __syncthreads();
    for (int s = 128; s > 0; s >>= 1) { if (t < s) red[t] += red[t + s]; __syncthreads(); }
    float pAp = red[0]; __syncthreads();
    red[t] = da * dfv; __syncthreads();
    for (int s = 128; s > 0; s >>= 1) { if (t < s) red[t] += red[t + s]; __syncthreads(); }
    if (t == 0) {
        ws[OFF_PAP + bk]   = pAp;
        ws[OFF_DPOS2 + bk] = fmaxf(red[0], EPS_);
    }
}

// ---------- main kernel: n-tile 128 (r17), frag-layout A reads (coalesced), zero-barrier ----------
__global__ __launch_bounds__(512) void k3(const unsigned short* __restrict__ AFH,
                                          const unsigned short* __restrict__ AFL,
                                          const unsigned short* __restrict__ PFH,
                                          const unsigned short* __restrict__ PFL,
                                          const unsigned short* __restrict__ NH,
                                          const float* __restrict__ pap,
                                          const float* __restrict__ dpos2,
                                          unsigned* __restrict__ mina,
                                          unsigned* __restrict__ minv) {
    __shared__ unsigned short Bh[128 * 256];           // 64 KB, 16B-block XOR-swizzled
    __shared__ float ep[3328];                         // 13.3 KB

    int lin = blockIdx.x;
    int x  = lin & 7;
    int q  = lin >> 3;
    int b  = q >> 4;
    int n0 = (x * 16 + (q & 15)) * 128;                // XCD-local 2048-n slice
    int t = threadIdx.x, lane = t & 63, w = t >> 6;
    int l15 = lane & 15, lg = lane >> 4;
    const unsigned short* Nh = NH + (size_t)n0 * 256;

    {   // one-shot swizzled staging of the 128x256 bf16 negative tile
        int row = t >> 2, q4 = t & 3, rsw = row & 7;
        const unsigned short* gh = Nh + (size_t)row * 256 + q4 * 64;
        #pragma unroll
        for (int k = 0; k < 8; ++k) {
            int sblk = (q4 * 8 + k) ^ rsw;
            *reinterpret_cast<short8*>(Bh + row * 256 + sblk * 8) =
                *reinterpret_cast<const short8*>(gh + k * 8);
        }
    }
    __syncthreads();                                   // the ONLY pre-compute barrier

    // frag-layout bases: AF[b][eb][row][i]; per chunk c: eb = c*4 + lg
    const unsigned short* aFh = AFH + (size_t)b * 65536 + (size_t)lg * 2048 + (w * 32 + l15) * 8;
    const unsigned short* aFl = AFL + (size_t)b * 65536 + (size_t)lg * 2048 + (w * 32 + l15) * 8;
    const unsigned short* pFh = PFH + (size_t)b * 4096 + (size_t)lg * 128 + l15 * 8;
    const unsigned short* pFl = PFL + (size_t)b * 4096 + (size_t)lg * 128 + l15 * 8;

    f32x4 acc0[8] = {}, acc1[8] = {};
    f32x4 accp = {};
    int rs0 = l15 & 7;

    #pragma unroll
    for (int c = 0; c < 8; ++c) {
        short8 ah0 = *reinterpret_cast<const short8*>(aFh + c * 8192);
        short8 al0 = *reinterpret_cast<const short8*>(aFl + c * 8192);
        short8 ah1 = *reinterpret_cast<const short8*>(aFh + c * 8192 + 128);
        short8 al1 = *reinterpret_cast<const short8*>(aFl + c * 8192 + 128);
        short8 ph_ = *reinterpret_cast<const short8*>(pFh + c * 512);
        short8 pl_ = *reinterpret_cast<const short8*>(pFl + c * 512);
        #pragma unroll
        for (int j = 0; j < 8; ++j) {
            int ro = (j * 16 + l15) * 256 + (((c * 4 + lg) ^ rs0) * 8);
            short8 bh = *reinterpret_cast<const short8*>(Bh + ro);
            acc0[j] = __builtin_amdgcn_mfma_f32_16x16x32_bf16(ah0, bh, acc0[j], 0, 0, 0);
            acc0[j] = __builtin_amdgcn_mfma_f32_16x16x32_bf16(al0, bh, acc0[j], 0, 0, 0);
            acc1[j] = __builtin_amdgcn_mfma_f32_16x16x32_bf16(ah1, bh, acc1[j], 0, 0, 0);
            acc1[j] = __builtin_amdgcn_mfma_f32_16x16x32_bf16(al1, bh, acc1[j], 0, 0, 0);
            if (w == j) {
                accp = __builtin_amdgcn_mfma_f32_16x16x32_bf16(ph_, bh, accp, 0, 0, 0);
                accp = __builtin_amdgcn_mfma_f32_16x16x32_bf16(pl_, bh, accp, 0, 0, 0);
            }
        }
    }

    float* pAn_l = ep;              // [128][17] = 2176 (live until d2 loop done)
    float* nAnp  = ep + 2176;       // [8][128] (dead after nAn reduce)
    float* nAn_l = ep + 3200;       // [128]
    float* reda  = ep + 2176;       // aliases nAnp (written after consumed)
    float* redv  = ep + 2688;       // aliases nAnp upper half

    #pragma unroll
    for (int r = 0; r < 4; ++r)
        pAn_l[(w * 16 + l15) * 17 + 4 * lg + r] = accp[r];

    int bb = w * 4 + (lg >> 1);
    int sub = (lg & 1) * 4;
    #pragma unroll
    for (int j = 0; j < 8; ++j) {
        int n = j * 16 + l15;
        float p = 0.f;
        {
            ushort4v wh0 = *reinterpret_cast<const ushort4v*>(Bh + n * 256 + ((bb    ) ^ rs0) * 8 + sub);
            ushort4v wh1 = *reinterpret_cast<const ushort4v*>(Bh + n * 256 + ((bb + 2) ^ rs0) * 8 + sub);
            #pragma unroll
            for (int r = 0; r < 4; ++r) {
                p = fmaf(acc0[j][r], bf_tof(wh0[r]), p);
                p = fmaf(acc1[j][r], bf_tof(wh1[r]), p);
            }
        }
        p += __shfl_xor(p, 16);
        p += __shfl_xor(p, 32);
        if (lane < 16) nAnp[w * 128 + n] = p;
    }
    __syncthreads();
    if (t < 128) {
        float s = 0.f;
        #pragma unroll
        for (int ww = 0; ww < 8; ++ww) s += nAnp[ww * 128 + t];
        nAn_l[t] = s;
    }
    __syncthreads();                                   // nAnp consumed; reda/redv may overwrite
    {
        int tx = t & 15, ty = t >> 4;
        float pApk = pap[b * 16 + tx];
        float dp2  = dpos2[b * 16 + tx];
        float mn_a = __uint_as_float(0x7f800000u), mn_v = mn_a;
        #pragma unroll
        for (int ii = 0; ii < 4; ++ii) {
            int n = ty * 4 + ii;
            float d2v = pApk - 2.f * pAn_l[n * 17 + tx] + nAn_l[n];
            float cc = fmaxf(d2v, EPS_);
            mn_a = fminf(mn_a, cc);
            if (cc > dp2) mn_v = fminf(mn_v, cc);
        }
        reda[ty * 16 + tx] = mn_a; redv[ty * 16 + tx] = mn_v;
    }
    __syncthreads();
    if (t < 16) {
        float ra = reda[t], rv = redv[t];
        #pragma unroll
        for (int y = 1; y < 32; ++y) {
            ra = fminf(ra, reda[y * 16 + t]);
            rv = fminf(rv, redv[y * 16 + t]);
        }
        atomicMin(&mina[b * 16 + t], __float_as_uint(ra));
        atomicMin(&minv[b * 16 + t], __float_as_uint(rv));
    }
}

// ---------- final loss ----------
__global__ __launch_bounds__(256) void k5(const float* __restrict__ dpos2,
                                          const unsigned* __restrict__ mina,
                                          const unsigned* __restrict__ minv,
                                          float* __restrict__ out) {
    int t = threadIdx.x;
    __shared__ float red[256];
    float dp = sqrtf(dpos2[t]);
    unsigned mv = minv[t], ma = mina[t];
    unsigned sel = (mv < 0x7f800000u) ? mv : ma;
    float dn = sqrtf(__uint_as_float(sel));
    red[t] = fmaxf(dp - dn + ALPHA_, 0.f);
    __syncthreads();
    for (int s = 128; s > 0; s >>= 1) { if (t < s) red[t] += red[t + s]; __syncthreads(); }
    if (t == 0) out[0] = red[0] * (1.f / 256.f);
}

extern "C" void kernel_launch(void* const* d_in, const int* in_sizes, int n_in,
                              void* d_out, int out_size, void* d_ws, size_t ws_size,
                              hipStream_t stream) {
    (void)in_sizes; (void)n_in; (void)out_size; (void)ws_size;
    const float* Z1   = (const float*)d_in[0];
    const float* Z2   = (const float*)d_in[1];
    const int*   mat  = (const int*)d_in[2];
    const float* negs = (const float*)d_in[3];
    const float* Sig  = (const float*)d_in[4];
    float* ws = (float*)d_ws;
    unsigned short* S_H  = (unsigned short*)(ws + OFF_S_H);
    unsigned short* S_L  = (unsigned short*)(ws + OFF_S_L);
    unsigned short* XA_H = (unsigned short*)(ws + OFF_XA_H);
    unsigned short* XA_L = (unsigned short*)(ws + OFF_XA_L);
    unsigned short* XB_H = (unsigned short*)(ws + OFF_XB_H);
    unsigned short* XB_L = (unsigned short*)(ws + OFF_XB_L);
    unsigned short* T_H  = (unsigned short*)(ws + OFF_T_H);
    unsigned short* T_L  = (unsigned short*)(ws + OFF_T_L);
    unsigned short* AF_H = (unsigned short*)(ws + OFF_AF_H);
    unsigned short* AF_L = (unsigned short*)(ws + OFF_AF_L);
    unsigned short* PA_H = (unsigned short*)(ws + OFF_PA_H);
    unsigned short* PA_L = (unsigned short*)(ws + OFF_PA_L);
    unsigned short* NH   = (unsigned short*)(ws + OFF_NH);
    unsigned* mina = (unsigned*)(ws + OFF_MINA);
    unsigned* minv = (unsigned*)(ws + OFF_MINV);
    float* out = (float*)d_out;

    kbound<<<BB, 256, 0, stream>>>(Sig, ws + OFF_C01);        // power-iter bound -> c0,c1
    kinit<<<4096, 256, 0, stream>>>(Sig, ws, ws + OFF_C01);   // split S; P0 = X0 -> XA

    // R0 = I - S@P0 -> T
    kmm<<<1024, 256, 0, stream>>>(S_H, S_L, XA_H, XA_L, T_H, T_L, 2, S_H, S_L, T_H, T_L);
    // stage 0: P1 = P0 + P0@R0 -> XB ; R1 = R0^2 -> S
    kmm<<<2048, 256, 0, stream>>>(XA_H, XA_L, T_H, T_L, XB_H, XB_L, 3, T_H, T_L, S_H, S_L);
    // stage 1: P2 = P1 + P1@R1 -> XA ; R2 = R1^2 -> T
    kmm<<<2048, 256, 0, stream>>>(XB_H, XB_L, S_H, S_L, XA_H, XA_L, 3, S_H, S_L, T_H, T_L);
    // stage 2: P3 = P2 + P2@R2 -> XB (FINAL A); residual = R0^8 ~ 8e-5
    kmm<<<1024, 256, 0, stream>>>(XA_H, XA_L, T_H, T_L, XB_H, XB_L, 3, S_H, S_L, T_H, T_L);

    // repack A into fragment layout (XA region now dead)
    kpack<<<512, 256, 0, stream>>>(XB_H, XB_L, AF_H, AF_L);
    // fused: negatives bf16 (+min init) and k2 (PA in frag layout)
    kaux<<<2048 + BB * KK, 256, 0, stream>>>(negs, NH, mina, minv,
                                             Z1, Z2, mat, XB_H, XB_L, ws);
    k3<<<BB * NNEG / 128, 512, 0, stream>>>(AF_H, AF_L, PA_H, PA_L, NH,
                                            ws + OFF_PAP, ws + OFF_DPOS2, mina, minv);
    k5<<<1, 256, 0, stream>>>(ws + OFF_DPOS2, mina, minv, out);
}